// Round 11
// baseline (238.585 us; speedup 1.0000x reference)
//
#include <hip/hip_runtime.h>
#include <hip/hip_bf16.h>

// FlashMultiHeadAttention: x -> QKV proj -> causal GQA flash attn -> out proj
// B=2 N=2048 E=2048 HQ=32 HKV=8 D=64 G=4. All compute in bf16 MFMA, fp32 accum.

#define B_   2
#define N_   2048
#define E_   2048
#define HQ_  32
#define HKV_ 8
#define D_   64
#define BN_  (B_*N_)   // 4096 total rows

typedef __attribute__((ext_vector_type(8))) short bf16x8;
typedef __attribute__((ext_vector_type(4))) float f32x4;

#define MFMA16(a,b,c) __builtin_amdgcn_mfma_f32_16x16x32_bf16(a,b,c,0,0,0)

__device__ inline unsigned short f2bf(float f) {
  unsigned u = __builtin_bit_cast(unsigned, f);
  u += 0x7FFFu + ((u >> 16) & 1u);   // RNE
  return (unsigned short)(u >> 16);
}

__device__ inline void gload_lds16(const void* g, void* l) {
  __builtin_amdgcn_global_load_lds(
      (const __attribute__((address_space(1))) void*)g,
      (__attribute__((address_space(3))) void*)l, 16, 0, 0);
}

// ---------------- fused cast fp32 -> bf16 for x,Wq,Wk,Wv,Wo ----------------
__global__ void cast_all(const float* __restrict__ x,  const float* __restrict__ wq,
                         const float* __restrict__ wk, const float* __restrict__ wv,
                         const float* __restrict__ wo, unsigned short* __restrict__ dst) {
  const int c0 = 2097152;            // x      (8388608 elems /4)
  const int c1 = c0 + 1048576;       // Wq
  const int c2 = c1 + 262144;        // Wk
  const int c3 = c2 + 262144;        // Wv
  const int c4 = c3 + 1048576;       // Wo
  int i = blockIdx.x * blockDim.x + threadIdx.x;
  const int stride = gridDim.x * blockDim.x;
  for (; i < c4; i += stride) {
    const float* src; int off;
    if      (i < c0) { src = x;  off = i; }
    else if (i < c1) { src = wq; off = i - c0; }
    else if (i < c2) { src = wk; off = i - c1; }
    else if (i < c3) { src = wv; off = i - c2; }
    else             { src = wo; off = i - c3; }
    float4 f = reinterpret_cast<const float4*>(src)[off];
    ushort4 u;
    u.x = f2bf(f.x); u.y = f2bf(f.y); u.z = f2bf(f.z); u.w = f2bf(f.w);
    reinterpret_cast<ushort4*>(dst)[i] = u;
  }
}

// ======== BK=32 3-stage counted-vmcnt GEMM engine (T3/T4-min, m201 mechanism) ====
// Tile 128x128, BK=32, 4 waves x 64x64. THREE buffer pairs (48KB LDS): at step t,
// issue stage(t+2); per-wave s_waitcnt vmcnt(8) (tile-t loads landed, t+1/t+2
// stay in flight ACROSS barriers); raw s_barrier; 8 ds_read_b128 + 16 MFMA; raw
// s_barrier (reads consumed => safe to overwrite buf at t+1). Staging/read
// swizzle identical to v10 (numerically verified, 0 bank conflicts):
// global chunk = lx^((li>>1)&3); ds_read chunk = kgrp^((cl>>1)&3).

// ---------------- fused QKV projection GEMM ----------------
__global__ __launch_bounds__(256) void gemm_qkv(
    const unsigned short* __restrict__ A,
    const unsigned short* __restrict__ Wq, const unsigned short* __restrict__ Wk,
    const unsigned short* __restrict__ Wv,
    const float* __restrict__ bq, const float* __restrict__ bk, const float* __restrict__ bv,
    unsigned short* __restrict__ Qo, unsigned short* __restrict__ Ko,
    unsigned short* __restrict__ Vto)
{
  __shared__ __align__(16) unsigned short As[3][128*32];   // 3 x 8KB
  __shared__ __align__(16) unsigned short Bs[3][128*32];   // 3 x 8KB
  const int tid  = threadIdx.x;
  const int w    = tid >> 6;
  const int lane = tid & 63;
  const int bm   = blockIdx.x / 24;
  const int bn   = blockIdx.x - bm * 24;
  const int m0   = bm << 7, n0 = bn << 7;
  const int K    = E_;

  const unsigned short* W; const float* bias; int wn0, seg;
  if      (n0 < 2048) { W = Wq; bias = bq; wn0 = n0;        seg = 0; }
  else if (n0 < 2560) { W = Wk; bias = bk; wn0 = n0 - 2048; seg = 1; }
  else                { W = Wv; bias = bv; wn0 = n0 - 2560; seg = 2; }

  const int wr   = (w >> 1) << 6;
  const int wc   = (w & 1) << 6;
  const int cl   = lane & 15;
  const int kgrp = lane >> 4;
  const int rl   = kgrp << 2;
  const int li   = lane >> 2;        // staging row-in-group 0..15
  const int lx   = lane & 3;         // staging chunk 0..3

  const unsigned gch = ((unsigned)(lx ^ ((li >> 1) & 3))) << 3;   // elems
  const unsigned short* gA = A + (size_t)(m0 + li) * K + gch;
  const unsigned short* gB = W + (size_t)(wn0 + li) * K + gch;

  const unsigned rch = ((unsigned)(kgrp ^ ((cl >> 1) & 3))) << 3;
  unsigned rAo[4], rBo[4];
  #pragma unroll
  for (int z = 0; z < 4; ++z) {
    rAo[z] = (unsigned)(wr + z*16 + cl) * 32u + rch;
    rBo[z] = (unsigned)(wc + z*16 + cl) * 32u + rch;
  }

  f32x4 acc[4][4] = {};
  const int nk = K >> 5;   // 64

  auto STAGE = [&](int kt, unsigned short* la, unsigned short* lb) {
    const int ko = kt << 5;
    #pragma unroll
    for (int q = 0; q < 2; ++q) {
      const int i = w*2 + q;
      gload_lds16(gA + (size_t)(i*16)*K + ko, la + i*512 + lane*8);
      gload_lds16(gB + (size_t)(i*16)*K + ko, lb + i*512 + lane*8);
    }
  };

  unsigned short *a0 = As[0], *a1 = As[1], *a2 = As[2];
  unsigned short *b0 = Bs[0], *b1 = Bs[1], *b2 = Bs[2];
  STAGE(0, a0, b0);
  STAGE(1, a1, b1);

  for (int kt = 0; kt < nk; ++kt) {
    if (kt + 2 < nk) STAGE(kt + 2, a2, b2);
    if (kt + 2 < nk)      asm volatile("s_waitcnt vmcnt(8)" ::: "memory");
    else if (kt + 1 < nk) asm volatile("s_waitcnt vmcnt(4)" ::: "memory");
    else                  asm volatile("s_waitcnt vmcnt(0)" ::: "memory");
    __builtin_amdgcn_s_barrier();          // all waves' tile-kt loads landed
    bf16x8 af[4], bfr[4];
    #pragma unroll
    for (int i = 0; i < 4; ++i)
      af[i] = *reinterpret_cast<const bf16x8*>(&a0[rAo[i]]);
    #pragma unroll
    for (int j = 0; j < 4; ++j)
      bfr[j] = *reinterpret_cast<const bf16x8*>(&b0[rBo[j]]);
    #pragma unroll
    for (int i = 0; i < 4; ++i)
      #pragma unroll
      for (int j = 0; j < 4; ++j)
        acc[i][j] = MFMA16(af[i], bfr[j], acc[i][j]);
    __builtin_amdgcn_s_barrier();          // reads of buf done before overwrite
    unsigned short* ta = a0; a0 = a1; a1 = a2; a2 = ta;
    unsigned short* tb = b0; b0 = b1; b1 = b2; b2 = tb;
  }

  if (seg == 0) {
    #pragma unroll
    for (int j = 0; j < 4; ++j) {
      const int col = wn0 + wc + j*16 + cl;
      const float bj = bias[col];
      #pragma unroll
      for (int i = 0; i < 4; ++i) {
        const int row = m0 + wr + i*16 + rl;
        #pragma unroll
        for (int r = 0; r < 4; ++r)
          Qo[(size_t)(row + r) * 2048 + col] = f2bf(acc[i][j][r] + bj);
      }
    }
  } else if (seg == 1) {
    #pragma unroll
    for (int j = 0; j < 4; ++j) {
      const int col = wn0 + wc + j*16 + cl;
      const float bj = bias[col];
      #pragma unroll
      for (int i = 0; i < 4; ++i) {
        const int row = m0 + wr + i*16 + rl;
        #pragma unroll
        for (int r = 0; r < 4; ++r)
          Ko[(size_t)(row + r) * 512 + col] = f2bf(acc[i][j][r] + bj);
      }
    }
  } else {
    // V transposed: Vt[col][row], ld = 4096
    #pragma unroll
    for (int j = 0; j < 4; ++j) {
      const int col = wn0 + wc + j*16 + cl;
      const float bj = bias[col];
      #pragma unroll
      for (int i = 0; i < 4; ++i) {
        const int rowb = m0 + wr + i*16 + rl;
        ushort4 u;
        u.x = f2bf(acc[i][j][0] + bj);
        u.y = f2bf(acc[i][j][1] + bj);
        u.z = f2bf(acc[i][j][2] + bj);
        u.w = f2bf(acc[i][j][3] + bj);
        *reinterpret_cast<ushort4*>(&Vto[(size_t)col * 4096 + rowb]) = u;
      }
    }
  }
}

// ---------------- out-proj GEMM (3-stage counted-vmcnt, fp32 out) ----------------
__global__ __launch_bounds__(256) void gemm_out(
    const unsigned short* __restrict__ A, const unsigned short* __restrict__ W,
    const float* __restrict__ bias, float* __restrict__ C)
{
  __shared__ __align__(16) unsigned short As[3][128*32];
  __shared__ __align__(16) unsigned short Bs[3][128*32];
  const int tid  = threadIdx.x;
  const int w    = tid >> 6;
  const int lane = tid & 63;
  const int bm   = blockIdx.x >> 4;
  const int bn   = blockIdx.x & 15;
  const int m0   = bm << 7, n0 = bn << 7;
  const int K    = E_;
  const int wr   = (w >> 1) << 6;
  const int wc   = (w & 1) << 6;
  const int cl   = lane & 15;
  const int kgrp = lane >> 4;
  const int rl   = kgrp << 2;
  const int li   = lane >> 2;
  const int lx   = lane & 3;

  const unsigned gch = ((unsigned)(lx ^ ((li >> 1) & 3))) << 3;
  const unsigned short* gA = A + (size_t)(m0 + li) * K + gch;
  const unsigned short* gB = W + (size_t)(n0 + li) * K + gch;

  const unsigned rch = ((unsigned)(kgrp ^ ((cl >> 1) & 3))) << 3;
  unsigned rAo[4], rBo[4];
  #pragma unroll
  for (int z = 0; z < 4; ++z) {
    rAo[z] = (unsigned)(wr + z*16 + cl) * 32u + rch;
    rBo[z] = (unsigned)(wc + z*16 + cl) * 32u + rch;
  }

  f32x4 acc[4][4] = {};
  const int nk = K >> 5;

  auto STAGE = [&](int kt, unsigned short* la, unsigned short* lb) {
    const int ko = kt << 5;
    #pragma unroll
    for (int q = 0; q < 2; ++q) {
      const int i = w*2 + q;
      gload_lds16(gA + (size_t)(i*16)*K + ko, la + i*512 + lane*8);
      gload_lds16(gB + (size_t)(i*16)*K + ko, lb + i*512 + lane*8);
    }
  };

  unsigned short *a0 = As[0], *a1 = As[1], *a2 = As[2];
  unsigned short *b0 = Bs[0], *b1 = Bs[1], *b2 = Bs[2];
  STAGE(0, a0, b0);
  STAGE(1, a1, b1);

  for (int kt = 0; kt < nk; ++kt) {
    if (kt + 2 < nk) STAGE(kt + 2, a2, b2);
    if (kt + 2 < nk)      asm volatile("s_waitcnt vmcnt(8)" ::: "memory");
    else if (kt + 1 < nk) asm volatile("s_waitcnt vmcnt(4)" ::: "memory");
    else                  asm volatile("s_waitcnt vmcnt(0)" ::: "memory");
    __builtin_amdgcn_s_barrier();
    bf16x8 af[4], bfr[4];
    #pragma unroll
    for (int i = 0; i < 4; ++i)
      af[i] = *reinterpret_cast<const bf16x8*>(&a0[rAo[i]]);
    #pragma unroll
    for (int j = 0; j < 4; ++j)
      bfr[j] = *reinterpret_cast<const bf16x8*>(&b0[rBo[j]]);
    #pragma unroll
    for (int i = 0; i < 4; ++i)
      #pragma unroll
      for (int j = 0; j < 4; ++j)
        acc[i][j] = MFMA16(af[i], bfr[j], acc[i][j]);
    __builtin_amdgcn_s_barrier();
    unsigned short* ta = a0; a0 = a1; a1 = a2; a2 = ta;
    unsigned short* tb = b0; b0 = b1; b1 = b2; b2 = tb;
  }

  #pragma unroll
  for (int j = 0; j < 4; ++j) {
    const int col = n0 + wc + j*16 + cl;
    const float bj = bias[col];
    #pragma unroll
    for (int i = 0; i < 4; ++i) {
      const int row = m0 + wr + i*16 + rl;
      #pragma unroll
      for (int r = 0; r < 4; ++r)
        C[(size_t)(row + r) * E_ + col] = acc[i][j][r] + bj;
    }
  }
}

// ---------------- causal GQA flash attention (v8: LDS-staged shared K/V) ----------
// grid (16, 32): x = bh = b*8+h, y = pair j. Block = 4 waves = the 4 query heads
// sharing (b,h)'s K/V. All waves handle the SAME balanced 32-row strip pair
// (j, 63-j) -> identical nt -> lockstep barriers. Per kv tile (64 kv): K tile and
// V^T tile (8KB each) staged into double-buffered LDS by 16 coalesced
// global_load_lds, stage-ahead of compute. Both-sides XOR chunk swizzle.
// Compute engine: S^T = mfma(K,Q), lane-local softmax, P via swizzled per-wave
// LDS, O^T = mfma(V^T,P), l via ones-MFMA.
__global__ __launch_bounds__(256, 2) void attn_kernel(
    const unsigned short* __restrict__ Q, const unsigned short* __restrict__ K,
    const unsigned short* __restrict__ Vt, unsigned short* __restrict__ O)
{
  __shared__ __align__(16) unsigned short Kbuf[2][4096];   // [64 kv][64 d] swizzled
  __shared__ __align__(16) unsigned short Vbuf[2][4096];   // [64 d][64 kv] swizzled
  __shared__ __align__(16) unsigned short Ps[4][2048];     // per-wave P
  const int tid  = threadIdx.x;
  const int w    = tid >> 6;
  const int lane = tid & 63;
  const int bh   = blockIdx.x;      // b*8 + h
  const int b    = bh >> 3;
  const int h    = bh & 7;
  const int j    = blockIdx.y;      // 0..31
  const int hq   = h*4 + w;         // this wave's query head
  const int cl   = lane & 15;
  const int kgrp = lane >> 4;
  const int rl   = kgrp << 2;
  const int li   = lane >> 3;       // 0..7 (staging row-in-group)
  const int lx   = lane & 7;        // 0..7 (staging chunk)

  const float K2 = 0.125f * 1.44269504088896340736f;  // SCALE * log2(e)

  char* pws = (char*)&Ps[w][0];
  const unsigned swz = ((unsigned)(cl & 7)) << 4;

  bf16x8 ones8;
  #pragma unroll
  for (int q = 0; q < 8; ++q) ones8[q] = (short)0x3F80;   // bf16 1.0

  const char* Kp = (const char*)(K + (size_t)(b*N_)*512 + h*64);
  const char* Vp = (const char*)(Vt + (size_t)(h*64)*BN_ + b*N_);

  // staging constants: instr i covers rows i*8+li; global chunk = (lx^li)
  const unsigned schunk = ((unsigned)(lx ^ li)) << 4;
  const unsigned kso  = (unsigned)li*1024u + schunk;   // + i*8192  + t*65536
  const unsigned vso  = (unsigned)li*8192u + schunk;   // + i*65536 + t*128
  const unsigned ldst = (unsigned)lane*16u;            // + i*1024

  // fragment read offsets: row z*16+cl, chunk (ks*4+kgrp)^(cl&7)
  unsigned rdo[4][2];
  #pragma unroll
  for (int z = 0; z < 4; ++z)
    #pragma unroll
    for (int ks = 0; ks < 2; ++ks)
      rdo[z][ks] = (unsigned)z*2048u + (unsigned)cl*128u
                 + ((((unsigned)ks*4u + (unsigned)kgrp) ^ (unsigned)(cl & 7)) << 4);

  // P LDS offsets: write b64 (4 kv), read b128 (8 kv)
  unsigned wb[2][4], rb[2][2];
  #pragma unroll
  for (int i = 0; i < 2; ++i) {
    #pragma unroll
    for (int c = 0; c < 4; ++c)
      wb[i][c] = (unsigned)i*2048u + (unsigned)cl*128u
               + (((unsigned)c*32u + (unsigned)kgrp*8u) ^ swz);
    #pragma unroll
    for (int ks = 0; ks < 2; ++ks)
      rb[i][ks] = (unsigned)i*2048u + (unsigned)cl*128u
                + (((unsigned)ks*64u + (unsigned)kgrp*16u) ^ swz);
  }

  for (int sp = 0; sp < 2; ++sp) {
    __syncthreads();   // protect LDS buffers from previous strip
    const int sidx = sp ? (63 - j) : j;
    const int q0   = sidx << 5;
    const int nt   = (sidx >> 1) + 1;   // kv tiles of 64

    // Q fragments (B-operand): lane cl = q row
    bf16x8 qf[2][2];
    #pragma unroll
    for (int i = 0; i < 2; ++i) {
      const size_t qoff = (size_t)(b*N_ + q0 + i*16 + cl) * E_ + hq*64 + (kgrp << 3);
      qf[i][0] = *reinterpret_cast<const bf16x8*>(Q + qoff);
      qf[i][1] = *reinterpret_cast<const bf16x8*>(Q + qoff + 32);
    }

    f32x4 o[2][4] = {};
    f32x4 l4[2] = {};
    float m[2] = {-1e30f, -1e30f};

    // stage tile 0 into buffer 0 (each wave: 2 K + 2 V instructions)
    #pragma unroll
    for (int q = 0; q < 2; ++q) {
      const unsigned i = (unsigned)(w*2 + q);
      gload_lds16(Kp + (i*8192u + kso),  (char*)Kbuf[0] + (i*1024u + ldst));
      gload_lds16(Vp + (i*65536u + vso), (char*)Vbuf[0] + (i*1024u + ldst));
    }
    int cur = 0;
    __syncthreads();   // drain stage

    for (int t = 0; t < nt; ++t) {
      // ---- stage tile t+1 into other buffer (overlaps with compute below) ----
      if (t + 1 < nt) {
        const unsigned kt = (unsigned)(t + 1) * 65536u;
        const unsigned vt = (unsigned)(t + 1) * 128u;
        #pragma unroll
        for (int q = 0; q < 2; ++q) {
          const unsigned i = (unsigned)(w*2 + q);
          gload_lds16(Kp + (kt + i*8192u + kso),  (char*)Kbuf[cur^1] + (i*1024u + ldst));
          gload_lds16(Vp + (vt + i*65536u + vso), (char*)Vbuf[cur^1] + (i*1024u + ldst));
        }
      }

      // ---- K fragments from LDS ----
      bf16x8 kf[4][2];
      #pragma unroll
      for (int c = 0; c < 4; ++c)
        #pragma unroll
        for (int ks = 0; ks < 2; ++ks)
          kf[c][ks] = *reinterpret_cast<const bf16x8*>((const char*)Kbuf[cur] + rdo[c][ks]);

      // ---- S^T = K Q ----
      f32x4 s[2][4];
      #pragma unroll
      for (int i = 0; i < 2; ++i)
        #pragma unroll
        for (int c = 0; c < 4; ++c) {
          f32x4 z = {};
          z = MFMA16(kf[c][0], qf[i][0], z);
          z = MFMA16(kf[c][1], qf[i][1], z);
          s[i][c] = z;
        }

      // ---- causal mask (last tile only): kv > q -> -inf ----
      if (t == nt - 1) {
        const int kvb = t << 6;
        #pragma unroll
        for (int i = 0; i < 2; ++i) {
          const int qq = q0 + i*16 + cl;
          #pragma unroll
          for (int c = 0; c < 4; ++c)
            #pragma unroll
            for (int r = 0; r < 4; ++r)
              if (kvb + c*16 + rl + r > qq) s[i][c][r] = -1e30f;
        }
      }

      // ---- softmax per i-block ----
      #pragma unroll
      for (int i = 0; i < 2; ++i) {
        float t0 = fmaxf(fmaxf(s[i][0][0], s[i][0][1]), fmaxf(s[i][0][2], s[i][0][3]));
        float t1 = fmaxf(fmaxf(s[i][1][0], s[i][1][1]), fmaxf(s[i][1][2], s[i][1][3]));
        float t2 = fmaxf(fmaxf(s[i][2][0], s[i][2][1]), fmaxf(s[i][2][2], s[i][2][3]));
        float t3 = fmaxf(fmaxf(s[i][3][0], s[i][3][1]), fmaxf(s[i][3][2], s[i][3][3]));
        float tm = fmaxf(fmaxf(t0, t1), fmaxf(t2, t3));
        tm = fmaxf(tm, __shfl_xor(tm, 16, 64));
        tm = fmaxf(tm, __shfl_xor(tm, 32, 64));
        const float mn = fmaxf(m[i], tm);
        const float al = __builtin_amdgcn_exp2f(K2 * (m[i] - mn));
        m[i] = mn;
        l4[i] *= al;
        #pragma unroll
        for (int db = 0; db < 4; ++db) o[i][db] *= al;
        #pragma unroll
        for (int c = 0; c < 4; ++c) {
          ushort4 u;
          u.x = f2bf(__builtin_amdgcn_exp2f(K2 * (s[i][c][0] - mn)));
          u.y = f2bf(__builtin_amdgcn_exp2f(K2 * (s[i][c][1] - mn)));
          u.z = f2bf(__builtin_amdgcn_exp2f(K2 * (s[i][c][2] - mn)));
          u.w = f2bf(__builtin_amdgcn_exp2f(K2 * (s[i][c][3] - mn)));
          *reinterpret_cast<ushort4*>(pws + wb[i][c]) = u;
        }
      }

      // ---- V fragments from LDS ----
      bf16x8 vf[4][2];
      #pragma unroll
      for (int db = 0; db < 4; ++db)
        #pragma unroll
        for (int ks = 0; ks < 2; ++ks)
          vf[db][ks] = *reinterpret_cast<const bf16x8*>((const char*)Vbuf[cur] + rdo[db][ks]);

      // ---- O^T += V^T P ; l += 1 . P ----
      #pragma unroll
      for (int i = 0; i < 2; ++i) {
        const bf16x8 pa0 = *reinterpret_cast<const bf16x8*>(pws + rb[i][0]);
        const bf16x8 pa1 = *reinterpret_cast<const bf16x8*>(pws + rb[i][1]);
        l4[i] = MFMA16(ones8, pa0, l4[i]);
        l4[i] = MFMA16(ones8, pa1, l4[i]);
        #pragma unroll
        for (int db = 0; db < 4; ++db) {
          o[i][db] = MFMA16(vf[db][0], pa0, o[i][db]);
          o[i][db] = MFMA16(vf[db][1], pa1, o[i][db]);
        }
      }

      __syncthreads();   // stage(t+1) drained + all waves done reading buf[cur]
      cur ^= 1;
    }

    // ---- epilogue: O[q][hq*64 + d] = o/l (contiguous ushort4 per (i,db)) ----
    #pragma unroll
    for (int i = 0; i < 2; ++i) {
      const float inv = 1.0f / l4[i][0];
      const size_t orow = (size_t)(b*N_ + q0 + i*16 + cl) * E_ + hq*64 + rl;
      #pragma unroll
      for (int db = 0; db < 4; ++db) {
        ushort4 u;
        u.x = f2bf(o[i][db][0] * inv);
        u.y = f2bf(o[i][db][1] * inv);
        u.z = f2bf(o[i][db][2] * inv);
        u.w = f2bf(o[i][db][3] * inv);
        *reinterpret_cast<ushort4*>(&O[orow + db*16]) = u;
      }
    }
  }
}

extern "C" void kernel_launch(void* const* d_in, const int* in_sizes, int n_in,
                              void* d_out, int out_size, void* d_ws, size_t ws_size,
                              hipStream_t stream) {
  const float* x  = (const float*)d_in[0];
  const float* Wq = (const float*)d_in[1];
  const float* bq = (const float*)d_in[2];
  const float* Wk = (const float*)d_in[3];
  const float* bk = (const float*)d_in[4];
  const float* Wv = (const float*)d_in[5];
  const float* bv = (const float*)d_in[6];
  const float* Wo = (const float*)d_in[7];
  const float* bo = (const float*)d_in[8];
  float* out = (float*)d_out;

  // workspace carve (bf16 elements); cast destinations contiguous in input order
  unsigned short* ws  = (unsigned short*)d_ws;
  unsigned short* xb  = ws;              // 4096x2048
  unsigned short* Wqb = xb  + 8388608;   // 2048x2048
  unsigned short* Wkb = Wqb + 4194304;   // 512x2048
  unsigned short* Wvb = Wkb + 1048576;   // 512x2048
  unsigned short* Wob = Wvb + 1048576;   // 2048x2048
  unsigned short* Qb  = Wob + 4194304;   // 4096x2048
  unsigned short* Kb  = Qb  + 8388608;   // 4096x512
  unsigned short* Vtb = Kb  + 2097152;   // 512x4096 (V transposed)
  unsigned short* Ob  = Vtb + 2097152;   // 4096x2048

  cast_all<<<dim3(2048), dim3(256), 0, stream>>>(x, Wq, Wk, Wv, Wo, xb);

  gemm_qkv<<<dim3(32*24), dim3(256), 0, stream>>>(xb, Wqb, Wkb, Wvb,
                                                  bq, bk, bv, Qb, Kb, Vtb);

  attn_kernel<<<dim3(16, 32), dim3(256), 0, stream>>>(Qb, Kb, Vtb, Ob);

  gemm_out<<<dim3(32*16), dim3(256), 0, stream>>>(Ob, Wob, bo, out);
}

// Round 12
// 195.325 us; speedup vs baseline: 1.2215x; 1.2215x over previous
//
#include <hip/hip_runtime.h>
#include <hip/hip_bf16.h>

// FlashMultiHeadAttention: x -> QKV proj -> causal GQA flash attn -> out proj
// B=2 N=2048 E=2048 HQ=32 HKV=8 D=64 G=4. All compute in bf16 MFMA, fp32 accum.

#define B_   2
#define N_   2048
#define E_   2048
#define HQ_  32
#define HKV_ 8
#define D_   64
#define BN_  (B_*N_)   // 4096 total rows

typedef __attribute__((ext_vector_type(8))) short bf16x8;
typedef __attribute__((ext_vector_type(4))) float f32x4;

#define MFMA16(a,b,c) __builtin_amdgcn_mfma_f32_16x16x32_bf16(a,b,c,0,0,0)

__device__ inline unsigned short f2bf(float f) {
  unsigned u = __builtin_bit_cast(unsigned, f);
  u += 0x7FFFu + ((u >> 16) & 1u);   // RNE
  return (unsigned short)(u >> 16);
}

__device__ inline void gload_lds16(const void* g, void* l) {
  __builtin_amdgcn_global_load_lds(
      (const __attribute__((address_space(1))) void*)g,
      (__attribute__((address_space(3))) void*)l, 16, 0, 0);
}

// ---------------- fused cast fp32 -> bf16 for x,Wq,Wk,Wv,Wo ----------------
__global__ void cast_all(const float* __restrict__ x,  const float* __restrict__ wq,
                         const float* __restrict__ wk, const float* __restrict__ wv,
                         const float* __restrict__ wo, unsigned short* __restrict__ dst) {
  const int c0 = 2097152;            // x      (8388608 elems /4)
  const int c1 = c0 + 1048576;       // Wq
  const int c2 = c1 + 262144;        // Wk
  const int c3 = c2 + 262144;        // Wv
  const int c4 = c3 + 1048576;       // Wo
  int i = blockIdx.x * blockDim.x + threadIdx.x;
  const int stride = gridDim.x * blockDim.x;
  for (; i < c4; i += stride) {
    const float* src; int off;
    if      (i < c0) { src = x;  off = i; }
    else if (i < c1) { src = wq; off = i - c0; }
    else if (i < c2) { src = wk; off = i - c1; }
    else if (i < c3) { src = wv; off = i - c2; }
    else             { src = wo; off = i - c3; }
    float4 f = reinterpret_cast<const float4*>(src)[off];
    ushort4 u;
    u.x = f2bf(f.x); u.y = f2bf(f.y); u.z = f2bf(f.z); u.w = f2bf(f.w);
    reinterpret_cast<ushort4*>(dst)[i] = u;
  }
}

// ---------------- fused QKV projection GEMM: 256x256 8-phase (m201 template) ------
// BM=BN=256, BK=64, 512 thr = 8 waves (2M x 4N), per-wave output 128x64
// (acc[8][4] f32x4). LDS 128KB: [2 dbuf][2 half] x 128x64 for A and B.
// Per K-tile: 4 phases (mq,ks); each phase: ds_read 4 A-frags (+4 B-frags on
// ks-change) || stage one half-pair of tile t+1 -> s_barrier -> setprio(1) +
// 16 MFMA + setprio(0) -> s_barrier. vmcnt ONCE per K-tile at tile end (staged
// halves were issued >=2.5 phases before deadline; nothing newer in flight).
// Staging/read swizzle = v8/v9-verified both-sides XOR (0 bank conflicts).
// Grid 192 = 8 XCD groups x 24: XCD g owns bm {2g,2g+1} x all bn (L2 locality).
__global__ __launch_bounds__(512, 2) void gemm_qkv(
    const unsigned short* __restrict__ A,
    const unsigned short* __restrict__ Wq, const unsigned short* __restrict__ Wk,
    const unsigned short* __restrict__ Wv,
    const float* __restrict__ bq, const float* __restrict__ bk, const float* __restrict__ bv,
    unsigned short* __restrict__ Qo, unsigned short* __restrict__ Ko,
    unsigned short* __restrict__ Vto)
{
  __shared__ __align__(16) unsigned short As[2][2][8192];  // [buf][half][128*64]
  __shared__ __align__(16) unsigned short Bs[2][2][8192];
  const int tid  = threadIdx.x;
  const int w    = tid >> 6;
  const int lane = tid & 63;
  const int g    = blockIdx.x & 7;       // XCD slot
  const int s    = blockIdx.x >> 3;      // 0..23
  const int bm   = g*2 + (s >= 12);
  const int bn   = (s >= 12) ? (s - 12) : s;
  const int m0   = bm << 8;
  const int n0v  = bn << 8;              // virtual col in [Q|K|V] = 3072
  const int K    = E_;

  const unsigned short* W; const float* bias; int wn0, seg;
  if      (n0v < 2048) { W = Wq; bias = bq; wn0 = n0v;        seg = 0; }
  else if (n0v < 2560) { W = Wk; bias = bk; wn0 = n0v - 2048; seg = 1; }
  else                 { W = Wv; bias = bv; wn0 = n0v - 2560; seg = 2; }

  const int mr   = w >> 2;               // wave m-half (0/1) -> rows mr*128..+128
  const int nc   = w & 3;                // wave n-col  -> cols nc*64..+64
  const int cl   = lane & 15;
  const int kgrp = lane >> 4;
  const int rl   = kgrp << 2;
  const int li   = lane >> 3;            // staging row-in-group 0..7
  const int lx   = lane & 7;             // staging chunk 0..7

  // staging bases: half h, wave rows w*16+q*8+li; global chunk = lx^li
  const unsigned gsw = ((unsigned)(lx ^ li)) << 3;   // elems
  const unsigned short* gA[2]; const unsigned short* gB[2];
  #pragma unroll
  for (int h = 0; h < 2; ++h) {
    gA[h] = A + (size_t)(m0  + h*128 + w*16 + li) * K + gsw;
    gB[h] = W + (size_t)(wn0 + h*128 + w*16 + li) * K + gsw;
  }
  const unsigned ldso = (unsigned)(w*16)*64u + (unsigned)lane*8u;  // elems in half
  const unsigned rsw  = (unsigned)(cl & 7);

  f32x4 acc[8][4] = {};
  const int nt = K >> 6;   // 32

  auto STAGE_P = [&](int kt, int buf, int h) {   // stage A-half h + B-half h of tile kt
    const int ko = kt << 6;
    #pragma unroll
    for (int q = 0; q < 2; ++q)
      gload_lds16(gA[h] + (size_t)(q*8)*K + ko, &As[buf][h][ldso + q*512]);
    #pragma unroll
    for (int q = 0; q < 2; ++q)
      gload_lds16(gB[h] + (size_t)(q*8)*K + ko, &Bs[buf][h][ldso + q*512]);
  };

  // prologue: tiles 0 and 1 fully staged
  STAGE_P(0, 0, 0); STAGE_P(0, 0, 1);
  STAGE_P(1, 1, 0); STAGE_P(1, 1, 1);
  asm volatile("s_waitcnt vmcnt(8)" ::: "memory");   // tile-0 landed, tile-1 in flight
  __builtin_amdgcn_s_barrier();

  for (int t = 0; t < nt; ++t) {
    const int p = t & 1;
    const unsigned short* Ah = As[p][mr];
    const unsigned short* Bh = Bs[p][nc >> 1];
    bf16x8 bfr[4];
    #pragma unroll
    for (int ph = 0; ph < 4; ++ph) {
      const int ks = ph >> 1, mq = ph & 1;
      bf16x8 af[4];
      #pragma unroll
      for (int z = 0; z < 4; ++z) {
        const unsigned row = (unsigned)(mq*64 + z*16 + cl);
        af[z] = *reinterpret_cast<const bf16x8*>(
            &Ah[row*64u + ((((unsigned)(ks*4 + kgrp)) ^ rsw) << 3)]);
      }
      if ((ph & 1) == 0) {   // B frags change only with ks (ph0, ph2)
        #pragma unroll
        for (int jj = 0; jj < 4; ++jj) {
          const unsigned row = (unsigned)((nc & 1)*64 + jj*16 + cl);
          bfr[jj] = *reinterpret_cast<const bf16x8*>(
              &Bh[row*64u + ((((unsigned)(ks*4 + kgrp)) ^ rsw) << 3)]);
        }
      }
      // stage tile t+1 halves at ph0/ph1 (target buffer p^1, freed after t-1)
      if (ph < 2 && t >= 1 && t + 1 < nt) STAGE_P(t + 1, p ^ 1, ph);
      __builtin_amdgcn_s_barrier();
      __builtin_amdgcn_s_setprio(1);
      #pragma unroll
      for (int z = 0; z < 4; ++z)
        #pragma unroll
        for (int jj = 0; jj < 4; ++jj)
          acc[mq*4 + z][jj] = MFMA16(af[z], bfr[jj], acc[mq*4 + z][jj]);
      __builtin_amdgcn_s_setprio(0);
      if (ph == 3) asm volatile("s_waitcnt vmcnt(0)" ::: "memory");  // next tile landed
      __builtin_amdgcn_s_barrier();
    }
  }

  // epilogue: rows m0 + mr*128 + (mi>>2)*64 + (mi&3)*16 + rl + r; cols wn0 + nc*64 + jj*16 + cl
  #pragma unroll
  for (int mi = 0; mi < 8; ++mi) {
    const int rowb = m0 + mr*128 + (mi >> 2)*64 + (mi & 3)*16 + rl;
    #pragma unroll
    for (int jj = 0; jj < 4; ++jj) {
      const int col = wn0 + nc*64 + jj*16 + cl;
      const float bj = bias[col];
      if (seg == 0) {
        #pragma unroll
        for (int r = 0; r < 4; ++r)
          Qo[(size_t)(rowb + r) * 2048 + col] = f2bf(acc[mi][jj][r] + bj);
      } else if (seg == 1) {
        #pragma unroll
        for (int r = 0; r < 4; ++r)
          Ko[(size_t)(rowb + r) * 512 + col] = f2bf(acc[mi][jj][r] + bj);
      } else {
        ushort4 u;
        u.x = f2bf(acc[mi][jj][0] + bj);
        u.y = f2bf(acc[mi][jj][1] + bj);
        u.z = f2bf(acc[mi][jj][2] + bj);
        u.w = f2bf(acc[mi][jj][3] + bj);
        *reinterpret_cast<ushort4*>(&Vto[(size_t)col * 4096 + rowb]) = u;
      }
    }
  }
}

// ---------------- out-proj GEMM (v9 engine: BK=64 single-buffer, fp32 out) --------
__global__ __launch_bounds__(256) void gemm_out(
    const unsigned short* __restrict__ A, const unsigned short* __restrict__ W,
    const float* __restrict__ bias, float* __restrict__ C)
{
  __shared__ __align__(16) unsigned short As[128*64];
  __shared__ __align__(16) unsigned short Bs[128*64];
  const int tid  = threadIdx.x;
  const int w    = tid >> 6;
  const int lane = tid & 63;
  const int bm   = blockIdx.x >> 4;
  const int bn   = blockIdx.x & 15;
  const int m0   = bm << 7, n0 = bn << 7;
  const int K    = E_;
  const int wr   = (w >> 1) << 6;
  const int wc   = (w & 1) << 6;
  const int cl   = lane & 15;
  const int kgrp = lane >> 4;
  const int rl   = kgrp << 2;
  const int li   = lane >> 3;
  const int lx   = lane & 7;

  const unsigned schunk = ((unsigned)(lx ^ li)) << 3;
  const unsigned short* gA = A + (size_t)(m0 + li) * K + schunk;
  const unsigned short* gB = W + (size_t)(n0 + li) * K + schunk;
  unsigned short* lA = As + lane*8;
  unsigned short* lB = Bs + lane*8;

  unsigned rA[4][2], rB[4][2];
  #pragma unroll
  for (int z = 0; z < 4; ++z)
    #pragma unroll
    for (int ks = 0; ks < 2; ++ks) {
      rA[z][ks] = (unsigned)(wr + z*16 + cl)*64u + ((((unsigned)ks*4u + (unsigned)kgrp) ^ (unsigned)(cl & 7)) << 3);
      rB[z][ks] = (unsigned)(wc + z*16 + cl)*64u + ((((unsigned)ks*4u + (unsigned)kgrp) ^ (unsigned)(cl & 7)) << 3);
    }

  f32x4 acc[4][4] = {};

  for (int kt = 0; kt < (K >> 6); ++kt) {
    const int ko = kt << 6;
    #pragma unroll
    for (int q = 0; q < 4; ++q) {
      const unsigned i = (unsigned)(w*4 + q);
      gload_lds16(gA + ((size_t)i*8*K + ko), lA + i*512);
      gload_lds16(gB + ((size_t)i*8*K + ko), lB + i*512);
    }
    __syncthreads();
    #pragma unroll
    for (int ks = 0; ks < 2; ++ks) {
      bf16x8 af[4], bfr[4];
      #pragma unroll
      for (int i = 0; i < 4; ++i)
        af[i] = *reinterpret_cast<const bf16x8*>(&As[rA[i][ks]]);
      #pragma unroll
      for (int j = 0; j < 4; ++j)
        bfr[j] = *reinterpret_cast<const bf16x8*>(&Bs[rB[j][ks]]);
      #pragma unroll
      for (int i = 0; i < 4; ++i)
        #pragma unroll
        for (int j = 0; j < 4; ++j)
          acc[i][j] = MFMA16(af[i], bfr[j], acc[i][j]);
    }
    __syncthreads();
  }

  #pragma unroll
  for (int j = 0; j < 4; ++j) {
    const int col = n0 + wc + j*16 + cl;
    const float bj = bias[col];
    #pragma unroll
    for (int i = 0; i < 4; ++i) {
      const int row = m0 + wr + i*16 + rl;
      #pragma unroll
      for (int r = 0; r < 4; ++r)
        C[(size_t)(row + r) * E_ + col] = acc[i][j][r] + bj;
    }
  }
}

// ---------------- causal GQA flash attention (v8: LDS-staged shared K/V) ----------
// grid (16, 32): x = bh = b*8+h, y = pair j. Block = 4 waves = the 4 query heads
// sharing (b,h)'s K/V. All waves handle the SAME balanced 32-row strip pair
// (j, 63-j) -> identical nt -> lockstep barriers. Per kv tile (64 kv): K tile and
// V^T tile (8KB each) staged into double-buffered LDS by 16 coalesced
// global_load_lds, stage-ahead of compute. Both-sides XOR chunk swizzle.
// Compute engine: S^T = mfma(K,Q), lane-local softmax, P via swizzled per-wave
// LDS, O^T = mfma(V^T,P), l via ones-MFMA.
__global__ __launch_bounds__(256, 2) void attn_kernel(
    const unsigned short* __restrict__ Q, const unsigned short* __restrict__ K,
    const unsigned short* __restrict__ Vt, unsigned short* __restrict__ O)
{
  __shared__ __align__(16) unsigned short Kbuf[2][4096];   // [64 kv][64 d] swizzled
  __shared__ __align__(16) unsigned short Vbuf[2][4096];   // [64 d][64 kv] swizzled
  __shared__ __align__(16) unsigned short Ps[4][2048];     // per-wave P
  const int tid  = threadIdx.x;
  const int w    = tid >> 6;
  const int lane = tid & 63;
  const int bh   = blockIdx.x;      // b*8 + h
  const int b    = bh >> 3;
  const int h    = bh & 7;
  const int j    = blockIdx.y;      // 0..31
  const int hq   = h*4 + w;         // this wave's query head
  const int cl   = lane & 15;
  const int kgrp = lane >> 4;
  const int rl   = kgrp << 2;
  const int li   = lane >> 3;       // 0..7 (staging row-in-group)
  const int lx   = lane & 7;        // 0..7 (staging chunk)

  const float K2 = 0.125f * 1.44269504088896340736f;  // SCALE * log2(e)

  char* pws = (char*)&Ps[w][0];
  const unsigned swz = ((unsigned)(cl & 7)) << 4;

  bf16x8 ones8;
  #pragma unroll
  for (int q = 0; q < 8; ++q) ones8[q] = (short)0x3F80;   // bf16 1.0

  const char* Kp = (const char*)(K + (size_t)(b*N_)*512 + h*64);
  const char* Vp = (const char*)(Vt + (size_t)(h*64)*BN_ + b*N_);

  // staging constants: instr i covers rows i*8+li; global chunk = (lx^li)
  const unsigned schunk = ((unsigned)(lx ^ li)) << 4;
  const unsigned kso  = (unsigned)li*1024u + schunk;   // + i*8192  + t*65536
  const unsigned vso  = (unsigned)li*8192u + schunk;   // + i*65536 + t*128
  const unsigned ldst = (unsigned)lane*16u;            // + i*1024

  // fragment read offsets: row z*16+cl, chunk (ks*4+kgrp)^(cl&7)
  unsigned rdo[4][2];
  #pragma unroll
  for (int z = 0; z < 4; ++z)
    #pragma unroll
    for (int ks = 0; ks < 2; ++ks)
      rdo[z][ks] = (unsigned)z*2048u + (unsigned)cl*128u
                 + ((((unsigned)ks*4u + (unsigned)kgrp) ^ (unsigned)(cl & 7)) << 4);

  // P LDS offsets: write b64 (4 kv), read b128 (8 kv)
  unsigned wb[2][4], rb[2][2];
  #pragma unroll
  for (int i = 0; i < 2; ++i) {
    #pragma unroll
    for (int c = 0; c < 4; ++c)
      wb[i][c] = (unsigned)i*2048u + (unsigned)cl*128u
               + (((unsigned)c*32u + (unsigned)kgrp*8u) ^ swz);
    #pragma unroll
    for (int ks = 0; ks < 2; ++ks)
      rb[i][ks] = (unsigned)i*2048u + (unsigned)cl*128u
                + (((unsigned)ks*64u + (unsigned)kgrp*16u) ^ swz);
  }

  for (int sp = 0; sp < 2; ++sp) {
    __syncthreads();   // protect LDS buffers from previous strip
    const int sidx = sp ? (63 - j) : j;
    const int q0   = sidx << 5;
    const int nt   = (sidx >> 1) + 1;   // kv tiles of 64

    // Q fragments (B-operand): lane cl = q row
    bf16x8 qf[2][2];
    #pragma unroll
    for (int i = 0; i < 2; ++i) {
      const size_t qoff = (size_t)(b*N_ + q0 + i*16 + cl) * E_ + hq*64 + (kgrp << 3);
      qf[i][0] = *reinterpret_cast<const bf16x8*>(Q + qoff);
      qf[i][1] = *reinterpret_cast<const bf16x8*>(Q + qoff + 32);
    }

    f32x4 o[2][4] = {};
    f32x4 l4[2] = {};
    float m[2] = {-1e30f, -1e30f};

    // stage tile 0 into buffer 0 (each wave: 2 K + 2 V instructions)
    #pragma unroll
    for (int q = 0; q < 2; ++q) {
      const unsigned i = (unsigned)(w*2 + q);
      gload_lds16(Kp + (i*8192u + kso),  (char*)Kbuf[0] + (i*1024u + ldst));
      gload_lds16(Vp + (i*65536u + vso), (char*)Vbuf[0] + (i*1024u + ldst));
    }
    int cur = 0;
    __syncthreads();   // drain stage

    for (int t = 0; t < nt; ++t) {
      // ---- stage tile t+1 into other buffer (overlaps with compute below) ----
      if (t + 1 < nt) {
        const unsigned kt = (unsigned)(t + 1) * 65536u;
        const unsigned vt = (unsigned)(t + 1) * 128u;
        #pragma unroll
        for (int q = 0; q < 2; ++q) {
          const unsigned i = (unsigned)(w*2 + q);
          gload_lds16(Kp + (kt + i*8192u + kso),  (char*)Kbuf[cur^1] + (i*1024u + ldst));
          gload_lds16(Vp + (vt + i*65536u + vso), (char*)Vbuf[cur^1] + (i*1024u + ldst));
        }
      }

      // ---- K fragments from LDS ----
      bf16x8 kf[4][2];
      #pragma unroll
      for (int c = 0; c < 4; ++c)
        #pragma unroll
        for (int ks = 0; ks < 2; ++ks)
          kf[c][ks] = *reinterpret_cast<const bf16x8*>((const char*)Kbuf[cur] + rdo[c][ks]);

      // ---- S^T = K Q ----
      f32x4 s[2][4];
      #pragma unroll
      for (int i = 0; i < 2; ++i)
        #pragma unroll
        for (int c = 0; c < 4; ++c) {
          f32x4 z = {};
          z = MFMA16(kf[c][0], qf[i][0], z);
          z = MFMA16(kf[c][1], qf[i][1], z);
          s[i][c] = z;
        }

      // ---- causal mask (last tile only): kv > q -> -inf ----
      if (t == nt - 1) {
        const int kvb = t << 6;
        #pragma unroll
        for (int i = 0; i < 2; ++i) {
          const int qq = q0 + i*16 + cl;
          #pragma unroll
          for (int c = 0; c < 4; ++c)
            #pragma unroll
            for (int r = 0; r < 4; ++r)
              if (kvb + c*16 + rl + r > qq) s[i][c][r] = -1e30f;
        }
      }

      // ---- softmax per i-block ----
      #pragma unroll
      for (int i = 0; i < 2; ++i) {
        float t0 = fmaxf(fmaxf(s[i][0][0], s[i][0][1]), fmaxf(s[i][0][2], s[i][0][3]));
        float t1 = fmaxf(fmaxf(s[i][1][0], s[i][1][1]), fmaxf(s[i][1][2], s[i][1][3]));
        float t2 = fmaxf(fmaxf(s[i][2][0], s[i][2][1]), fmaxf(s[i][2][2], s[i][2][3]));
        float t3 = fmaxf(fmaxf(s[i][3][0], s[i][3][1]), fmaxf(s[i][3][2], s[i][3][3]));
        float tm = fmaxf(fmaxf(t0, t1), fmaxf(t2, t3));
        tm = fmaxf(tm, __shfl_xor(tm, 16, 64));
        tm = fmaxf(tm, __shfl_xor(tm, 32, 64));
        const float mn = fmaxf(m[i], tm);
        const float al = __builtin_amdgcn_exp2f(K2 * (m[i] - mn));
        m[i] = mn;
        l4[i] *= al;
        #pragma unroll
        for (int db = 0; db < 4; ++db) o[i][db] *= al;
        #pragma unroll
        for (int c = 0; c < 4; ++c) {
          ushort4 u;
          u.x = f2bf(__builtin_amdgcn_exp2f(K2 * (s[i][c][0] - mn)));
          u.y = f2bf(__builtin_amdgcn_exp2f(K2 * (s[i][c][1] - mn)));
          u.z = f2bf(__builtin_amdgcn_exp2f(K2 * (s[i][c][2] - mn)));
          u.w = f2bf(__builtin_amdgcn_exp2f(K2 * (s[i][c][3] - mn)));
          *reinterpret_cast<ushort4*>(pws + wb[i][c]) = u;
        }
      }

      // ---- V fragments from LDS ----
      bf16x8 vf[4][2];
      #pragma unroll
      for (int db = 0; db < 4; ++db)
        #pragma unroll
        for (int ks = 0; ks < 2; ++ks)
          vf[db][ks] = *reinterpret_cast<const bf16x8*>((const char*)Vbuf[cur] + rdo[db][ks]);

      // ---- O^T += V^T P ; l += 1 . P ----
      #pragma unroll
      for (int i = 0; i < 2; ++i) {
        const bf16x8 pa0 = *reinterpret_cast<const bf16x8*>(pws + rb[i][0]);
        const bf16x8 pa1 = *reinterpret_cast<const bf16x8*>(pws + rb[i][1]);
        l4[i] = MFMA16(ones8, pa0, l4[i]);
        l4[i] = MFMA16(ones8, pa1, l4[i]);
        #pragma unroll
        for (int db = 0; db < 4; ++db) {
          o[i][db] = MFMA16(vf[db][0], pa0, o[i][db]);
          o[i][db] = MFMA16(vf[db][1], pa1, o[i][db]);
        }
      }

      __syncthreads();   // stage(t+1) drained + all waves done reading buf[cur]
      cur ^= 1;
    }

    // ---- epilogue: O[q][hq*64 + d] = o/l (contiguous ushort4 per (i,db)) ----
    #pragma unroll
    for (int i = 0; i < 2; ++i) {
      const float inv = 1.0f / l4[i][0];
      const size_t orow = (size_t)(b*N_ + q0 + i*16 + cl) * E_ + hq*64 + rl;
      #pragma unroll
      for (int db = 0; db < 4; ++db) {
        ushort4 u;
        u.x = f2bf(o[i][db][0] * inv);
        u.y = f2bf(o[i][db][1] * inv);
        u.z = f2bf(o[i][db][2] * inv);
        u.w = f2bf(o[i][db][3] * inv);
        *reinterpret_cast<ushort4*>(&O[orow + db*16]) = u;
      }
    }
  }
}

extern "C" void kernel_launch(void* const* d_in, const int* in_sizes, int n_in,
                              void* d_out, int out_size, void* d_ws, size_t ws_size,
                              hipStream_t stream) {
  const float* x  = (const float*)d_in[0];
  const float* Wq = (const float*)d_in[1];
  const float* bq = (const float*)d_in[2];
  const float* Wk = (const float*)d_in[3];
  const float* bk = (const float*)d_in[4];
  const float* Wv = (const float*)d_in[5];
  const float* bv = (const float*)d_in[6];
  const float* Wo = (const float*)d_in[7];
  const float* bo = (const float*)d_in[8];
  float* out = (float*)d_out;

  // workspace carve (bf16 elements); cast destinations contiguous in input order
  unsigned short* ws  = (unsigned short*)d_ws;
  unsigned short* xb  = ws;              // 4096x2048
  unsigned short* Wqb = xb  + 8388608;   // 2048x2048
  unsigned short* Wkb = Wqb + 4194304;   // 512x2048
  unsigned short* Wvb = Wkb + 1048576;   // 512x2048
  unsigned short* Wob = Wvb + 1048576;   // 2048x2048
  unsigned short* Qb  = Wob + 4194304;   // 4096x2048
  unsigned short* Kb  = Qb  + 8388608;   // 4096x512
  unsigned short* Vtb = Kb  + 2097152;   // 512x4096 (V transposed)
  unsigned short* Ob  = Vtb + 2097152;   // 4096x2048

  cast_all<<<dim3(2048), dim3(256), 0, stream>>>(x, Wq, Wk, Wv, Wo, xb);

  gemm_qkv<<<dim3(192), dim3(512), 0, stream>>>(xb, Wqb, Wkb, Wvb,
                                                bq, bk, bv, Qb, Kb, Vtb);

  attn_kernel<<<dim3(16, 32), dim3(256), 0, stream>>>(Qb, Kb, Vtb, Ob);

  gemm_out<<<dim3(32*16), dim3(256), 0, stream>>>(Ob, Wob, bo, out);
}